// Round 12
// baseline (416.224 us; speedup 1.0000x reference)
//
#include <hip/hip_runtime.h>

// ---------------------------------------------------------------------------
// Triplane sample + 4-layer MLP, N=1e6 points. 2 dispatches:
//   D1 prep_kernel: [blocks 0..3071] transpose planes f32->f16 (x256, chan-
//       contiguous); [3072..3215] weights f32->f16.
//   D2 fused_kernel: sample 128 pts/block (original order) -> LDS feats ->
//       pair-split MFMA MLP -> out[p] (coalesced).
// Scale S=256 keeps f16 in normal range; epilogues add S*b in fp32; final
// layer divides by S in fp32.
//
// R1 (FAILED, 294us): 32-pt waves -> ILP collapse + 2x W traffic.
// R2 (NEUTRAL): pair-split 4 blk/CU; by-ref acc spilled (WRITE 70MB).
// R3 (NEUTRAL, 177us): de-spilled mlp; latency-chain bound.
// R4 (WIN, 598->509us): fused sample+MLP.
// R5/R6 (FAILED, ~800us): coop sort intrinsically stall-bound. Abandoned.
// R7 (WIN, 446us): dropped Morton sort; fused 287us, FETCH 577MB, occ 44%.
// R8 (FAILED, 750us): (128,5) reg cap -> catastrophic spill; but the
//   [64][128]+hswz swizzled-LDS layout itself PASSED correctness.
// R9 (WIN, 415us): de-unioned hot paths -> WRITE 113->3.9MB, fused 253us.
// R10 (FAILED): fp8 planes absmax 4.3e-6 > 1.9e-6 threshold. Reverted.
// R11 (NEUTRAL): source-level load pipelining -- hipcc's pressure-minimizing
//   scheduler re-serialized (VGPR stayed 64, dur unchanged). Source ILP is
//   a dead lever; phase 1 reverted to R9 form.
// R12: occupancy via LDS trim. Replace HPAD=136 pad with R8's verified
//   16B-chunk XOR swizzle (hswz: chunk ^= row&15) -> H = [2][64][128],
//   LDS 34816->32768 B -> exactly 5 blocks/CU = 20 waves/CU (+25% waves,
//   +25% outstanding gather misses). Geometry/launch bounds unchanged
//   (256,4); VGPR=64 allows 8 waves/SIMD so LDS is the sole cap.
// ---------------------------------------------------------------------------

#define SF 256.0f
#define FSTR 40   // halves per point-row for LDS feats overlay (32 + 8 pad)

typedef _Float16 half8 __attribute__((ext_vector_type(8)));
typedef _Float16 half4_t __attribute__((ext_vector_type(4)));
typedef float f32x4 __attribute__((ext_vector_type(4)));

__device__ __attribute__((always_inline)) inline half8 ld16(const _Float16* p) {
  return *reinterpret_cast<const half8*>(p);
}
__device__ __attribute__((always_inline)) inline void st16(_Float16* p, half8 v) {
  *reinterpret_cast<half8*>(p) = v;
}
// half-index of the 16B chunk (8 halves) `c` in swizzled row `r` of a
// [64][128]-half buffer. Verified correct in R8. For fixed chunk c, lanes
// r=0..15 map to 16 distinct chunks -> 2 lanes/bank on b128 reads (free).
__device__ __attribute__((always_inline)) inline int hswz(int r, int c) {
  return r * 128 + ((c ^ (r & 15)) << 3);
}

// ---------------- D1: prep (plane transpose + weights convert) -------------
__global__ __launch_bounds__(256) void prep_kernel(
    const float* __restrict__ planes, _Float16* __restrict__ ph,
    const float* __restrict__ w0, const float* __restrict__ w1,
    const float* __restrict__ w2, _Float16* __restrict__ w0h,
    _Float16* __restrict__ w1h, _Float16* __restrict__ w2h) {
  int bid = blockIdx.x;
  if (bid < 3072) {
    // plane transpose+convert+scale: 3*2^18 threads exactly
    int t = bid * 256 + threadIdx.x;
    int pid = t >> 18;
    int rem = t & ((1 << 18) - 1);              // y*512 + x
    const float* src = planes + ((size_t)pid << 23) + rem;  // [pid][c][y][x]
    half8 o[4];  // statically indexed after unroll -> registers
#pragma unroll
    for (int c = 0; c < 32; c++)
      o[c >> 3][c & 7] = (_Float16)(src[(size_t)c << 18] * SF);
    _Float16* dst = ph + ((size_t)t << 5);
#pragma unroll
    for (int i = 0; i < 4; i++) st16(dst + i * 8, o[i]);
  } else {
    // weights f32 -> f16: 36864 threads exactly (144 blocks)
    int t = (bid - 3072) * 256 + threadIdx.x;
    if (t < 4096) w0h[t] = (_Float16)w0[t];
    else if (t < 20480) w1h[t - 4096] = (_Float16)w1[t - 4096];
    else w2h[t - 20480] = (_Float16)w2[t - 20480];
  }
}

// ---------------- bilinear sampling: 16 channels (hf selects half) --------
// De-unioned (R9): half8 vector loads + per-element (float) extracts.
__device__ __attribute__((always_inline)) inline void samp16(
    const _Float16* __restrict__ pl, float X, float Y, int hf, float* acc) {
  float fx = (X + 1.0f) * 0.5f * 511.0f;
  float fy = (Y + 1.0f) * 0.5f * 511.0f;
  float x0f = floorf(fx), y0f = floorf(fy);
  float wx1 = fx - x0f, wy1 = fy - y0f;
  float wx0 = 1.0f - wx1, wy0 = 1.0f - wy1;
  int x0 = (int)x0f, y0 = (int)y0f;
  int x1 = x0 + 1, y1 = y0 + 1;
  float vx0 = (x0 >= 0 && x0 < 512) ? 1.0f : 0.0f;
  float vx1 = (x1 >= 0 && x1 < 512) ? 1.0f : 0.0f;
  float vy0 = (y0 >= 0 && y0 < 512) ? 1.0f : 0.0f;
  float vy1 = (y1 >= 0 && y1 < 512) ? 1.0f : 0.0f;
  int xc0 = min(max(x0, 0), 511), xc1 = min(max(x1, 0), 511);
  int yc0 = min(max(y0, 0), 511), yc1 = min(max(y1, 0), 511);
  float w00 = wx0 * wy0 * vx0 * vy0, w10 = wx1 * wy0 * vx1 * vy0;
  float w01 = wx0 * wy1 * vx0 * vy1, w11 = wx1 * wy1 * vx1 * vy1;
  const _Float16* p00 = pl + ((((size_t)yc0 << 9) + xc0) << 5) + hf * 16;
  const _Float16* p10 = pl + ((((size_t)yc0 << 9) + xc1) << 5) + hf * 16;
  const _Float16* p01 = pl + ((((size_t)yc1 << 9) + xc0) << 5) + hf * 16;
  const _Float16* p11 = pl + ((((size_t)yc1 << 9) + xc1) << 5) + hf * 16;
#pragma unroll
  for (int ch = 0; ch < 2; ch++) {
    half8 a = ld16(p00 + ch * 8);
    half8 b = ld16(p10 + ch * 8);
    half8 c = ld16(p01 + ch * 8);
    half8 d = ld16(p11 + ch * 8);
#pragma unroll
    for (int j = 0; j < 8; j++) {
      acc[ch * 8 + j] += w00 * (float)a[j] + w10 * (float)b[j] +
                         w01 * (float)c[j] + w11 * (float)d[j];
    }
  }
}

// ---------------- D2: fused sample + MLP ----------------
// Block = 256 threads = 2 pairs = 128 points; LDS 32768 B -> 5 blocks/CU
// (20 waves/CU). H per pair = [64][128] halves, hswz chunk swizzle.
// Phase 1: 2 threads/pt sample 16ch each -> LDS feats (FSTR stride,
//   unswizzled overlay). Phase 2: pair-split MLP -- wave w owns hidden
//   rows 64w..64w+63; MACRO body, per-mt fused epilogue: no spill.
#define LAYER_PAIR(Wg, bias)                                                   \
  {                                                                            \
    half8 Bf[4][4]; /* [nt][ks] : 64 regs */                                   \
    _Pragma("unroll") for (int nt = 0; nt < 4; nt++)                           \
    _Pragma("unroll") for (int ks = 0; ks < 4; ks++)                           \
        Bf[nt][ks] = ld16(&H[hswz(nt * 16 + n16, 4 * ks + g)]);                \
    __syncthreads(); /* all H reads done; safe to overwrite */                 \
    _Pragma("unroll") for (int mt = 0; mt < 4; mt++) {                         \
      f32x4 acc[4];                                                            \
      _Pragma("unroll") for (int nt = 0; nt < 4; nt++) acc[nt] = Z4;           \
      _Pragma("unroll") for (int ks = 0; ks < 4; ks++) {                       \
        half8 A = ld16((Wg) + ((w * 4 + mt) * 16 + n16) * 128 + ks * 32 + g * 8); \
        _Pragma("unroll") for (int nt = 0; nt < 4; nt++)                       \
            acc[nt] = __builtin_amdgcn_mfma_f32_16x16x32_f16(A, Bf[nt][ks],    \
                                                             acc[nt], 0, 0, 0); \
      }                                                                        \
      int gm = w * 4 + mt;                                                     \
      f32x4 bb = *reinterpret_cast<const f32x4*>((bias) + gm * 16 + g * 4);    \
      _Pragma("unroll") for (int nt = 0; nt < 4; nt++) {                       \
        half4_t v;                                                             \
        _Pragma("unroll") for (int r = 0; r < 4; r++)                          \
            v[r] = (_Float16)fmaxf(acc[nt][r] + SF * bb[r], 0.0f);             \
        *reinterpret_cast<half4_t*>(                                           \
            &H[hswz(nt * 16 + n16, 2 * gm + (g >> 1)) + (g & 1) * 4]) = v;     \
      }                                                                        \
    }                                                                          \
    __syncthreads(); /* H writes visible to partner */                         \
  }

__global__ __launch_bounds__(256, 4) void fused_kernel(
    const float* __restrict__ coords, const _Float16* __restrict__ ph,
    const _Float16* __restrict__ w0h, const _Float16* __restrict__ w1h,
    const _Float16* __restrict__ w2h, const float* __restrict__ b0,
    const float* __restrict__ b1, const float* __restrict__ b2,
    const float* __restrict__ w3, const float* __restrict__ b3,
    float* __restrict__ out, int npts) {
  __shared__ alignas(16) _Float16 hbuf[2][64 * 128];  // 32768 B -> 5 blk/CU
  int tid = threadIdx.x;
  int sb = blockIdx.x;  // natural order: coalesced coords reads + out writes

  // ---- phase 1: sample 128 points; 2 threads/pt, 16 channels each ----
  {
    int ptl = tid >> 1, hf = tid & 1;  // waves 0,1 cover pair0; 2,3 pair1
    long pb = (long)sb * 128 + (ptl >> 6) * 64;
    if (pb + 64 > npts) pb = npts - 64;  // tail: duplicate identical work
    long pp = pb + (ptl & 63);
    float cx = coords[3 * pp + 0];
    float cy = coords[3 * pp + 1];
    float cz = coords[3 * pp + 2];
    float acc[16];
#pragma unroll
    for (int c = 0; c < 16; c++) acc[c] = 0.0f;
    samp16(ph, cx, cy, hf, acc);                  // plane 0: (x, y)
    samp16(ph + (1u << 23), cy, cz, hf, acc);     // plane 1: (y, z)
    samp16(ph + (2u << 23), cx, cz, hf, acc);     // plane 2: (x, z)
    half8 u0, u1;  // static indices -> registers (no unions: R9 rule)
#pragma unroll
    for (int c = 0; c < 8; c++) u0[c] = (_Float16)acc[c];
#pragma unroll
    for (int c = 0; c < 8; c++) u1[c] = (_Float16)acc[8 + c];
    _Float16* F = hbuf[ptl >> 6];
    // feats row stride FSTR=40 halves (80B); max idx 2552 < 8192
    st16(&F[(ptl & 63) * FSTR + hf * 16], u0);
    st16(&F[(ptl & 63) * FSTR + hf * 16 + 8], u1);
  }
  __syncthreads();  // feats visible to all waves

  // ---- phase 2: pair-split MLP ----
  int wv = tid >> 6, lane = tid & 63;
  int pair = wv >> 1, w = wv & 1;
  int n16 = lane & 15, g = lane >> 4;
  long base = (long)sb * 128 + pair * 64;
  if (base + 64 > npts) base = npts - 64;  // same clamp as phase 1
  _Float16* H = hbuf[pair];
  const f32x4 Z4 = {0.0f, 0.0f, 0.0f, 0.0f};

  // layer 0: C^T = W0(rows 64w..64w+63, x32) * feats^T(32x64); K=32.
  {
    half8 Bf[4];
#pragma unroll
    for (int nt = 0; nt < 4; nt++)
      Bf[nt] = ld16(&H[(nt * 16 + n16) * FSTR + g * 8]);  // LDS feats
    __syncthreads();  // feats reads done; epilogue may overwrite region
#pragma unroll
    for (int mt = 0; mt < 4; mt++) {
      half8 A = ld16(w0h + ((w * 4 + mt) * 16 + n16) * 32 + g * 8);
      f32x4 acc[4];
#pragma unroll
      for (int nt = 0; nt < 4; nt++)
        acc[nt] = __builtin_amdgcn_mfma_f32_16x16x32_f16(A, Bf[nt], Z4, 0, 0, 0);
      int gm = w * 4 + mt;
      f32x4 bb = *reinterpret_cast<const f32x4*>(b0 + gm * 16 + g * 4);
#pragma unroll
      for (int nt = 0; nt < 4; nt++) {
        half4_t v;
#pragma unroll
        for (int r = 0; r < 4; r++)
          v[r] = (_Float16)fmaxf(acc[nt][r] + SF * bb[r], 0.0f);
        *reinterpret_cast<half4_t*>(
            &H[hswz(nt * 16 + n16, 2 * gm + (g >> 1)) + (g & 1) * 4]) = v;
      }
    }
    __syncthreads();  // H(L0) visible before L1 reads
  }

  LAYER_PAIR(w1h, b1)
  LAYER_PAIR(w2h, b2)

  // layer 3: out = dot(h2, w3)/S + b3, fp32 VALU.
  // Pair covers 64 pts; wave w takes pts w*32..+31. lane = pt' + 32*half;
  // each half does 8 of 16 chunks, reduce across halves via shfl_xor(32).
  int ptl3 = lane & 31, hh = lane >> 5;
  int pt = w * 32 + ptl3;
  float o = 0.0f;
#pragma unroll
  for (int ii = 0; ii < 8; ii++) {
    int i = hh * 8 + ii;
    half8 hv = ld16(&H[hswz(pt, i)]);
#pragma unroll
    for (int j = 0; j < 8; j++) o += (float)hv[j] * w3[i * 8 + j];
  }
  o += __shfl_xor(o, 32);
  if (lane < 32) {
    out[base + pt] = o * (1.0f / SF) + b3[0];  // coalesced
  }
}

// ---------------- launch ----------------
extern "C" void kernel_launch(void* const* d_in, const int* in_sizes, int n_in,
                              void* d_out, int out_size, void* d_ws, size_t ws_size,
                              hipStream_t stream) {
  const float* coords = (const float*)d_in[0];
  const float* planes = (const float*)d_in[1];
  const float* w0 = (const float*)d_in[2];
  const float* b0 = (const float*)d_in[3];
  const float* w1 = (const float*)d_in[4];
  const float* b1 = (const float*)d_in[5];
  const float* w2 = (const float*)d_in[6];
  const float* b2 = (const float*)d_in[7];
  const float* w3 = (const float*)d_in[8];
  const float* b3 = (const float*)d_in[9];
  float* out = (float*)d_out;
  int npts = in_sizes[0] / 3;  // 1,000,000

  // workspace layout (bytes):
  //   ph       @ 0          50,331,648
  //   w0h      @ 50331648   8,192
  //   w1h      @ 50339840   32,768
  //   w2h      @ 50372608   32,768
  char* ws = (char*)d_ws;
  _Float16* ph = (_Float16*)ws;
  _Float16* w0h = (_Float16*)(ws + 50331648);
  _Float16* w1h = (_Float16*)(ws + 50339840);
  _Float16* w2h = (_Float16*)(ws + 50372608);

  int fblk = (npts + 127) / 128;  // 128 pts per block (2 pairs)

  // D1: transpose (3072) + weights (144) = 3216 blocks
  prep_kernel<<<3216, 256, 0, stream>>>(planes, ph, w0, w1, w2, w0h, w1h, w2h);
  // D2: fused sample + MLP, original point order
  fused_kernel<<<fblk, 256, 0, stream>>>(coords, ph, w0h, w1h, w2h, b0, b1, b2,
                                         w3, b3, out, npts);
}